// Round 3
// baseline (4320.147 us; speedup 1.0000x reference)
//
#include <hip/hip_runtime.h>
#include <hip/hip_bf16.h>

#define S 4096
#define E 256
#define HH 256
#define G4 1024
#define TT 16
#define NEG_ -10000.0f
#define START_ 14
#define STOP_ 15

// ---------- fast math helpers ----------
__device__ __forceinline__ float fast_exp(float x) {           // e^x
    return __builtin_amdgcn_exp2f(x * 1.4426950408889634f);
}
__device__ __forceinline__ float fast_sigmoid(float x) {
    float e = __builtin_amdgcn_exp2f(-1.4426950408889634f * x);
    return __builtin_amdgcn_rcpf(1.0f + e);
}
__device__ __forceinline__ float fast_tanh(float x) {
    float xx = fminf(fmaxf(x, -30.f), 30.f);
    float e = __builtin_amdgcn_exp2f(2.8853900817779268f * xx); // e^{2x}
    return (e - 1.0f) * __builtin_amdgcn_rcpf(e + 1.0f);
}
__device__ __forceinline__ float fast_log(float x) {           // ln
    return 0.6931471805599453f * __builtin_amdgcn_logf(x);
}

#if __has_builtin(__builtin_amdgcn_sdot4)
__device__ __forceinline__ int dot4(int a, int b, int c) {
    return __builtin_amdgcn_sdot4(a, b, c, false);
}
#else
__device__ __forceinline__ int dot4(int a, int b, int c) {
    int d;
    asm("v_dot4_i32_i8 %0, %1, %2, %3" : "=v"(d) : "v"(a), "v"(b), "v"(c));
    return d;
}
#endif

// ---------- K0: quantize W_hh (per-row int8) and h0 ----------
__global__ __launch_bounds__(64) void quant_kernel(
    const float* __restrict__ Wf, const float* __restrict__ Wb,
    const float* __restrict__ h0,
    int* __restrict__ wq, float* __restrict__ wscale,
    int* __restrict__ hq0, float* __restrict__ sh0)
{
    int blk = blockIdx.x, lane = threadIdx.x;  // 64 threads = 1 wave
    const float* src;
    if (blk < 2048) {
        int d = blk >> 10, r = blk & 1023;
        src = (d == 0 ? Wf : Wb) + (size_t)r * 256;
        float4 v = ((const float4*)src)[lane];
        float m = fmaxf(fmaxf(fabsf(v.x), fabsf(v.y)), fmaxf(fabsf(v.z), fabsf(v.w)));
        #pragma unroll
        for (int off = 1; off < 64; off <<= 1) m = fmaxf(m, __shfl_xor(m, off, 64));
        float inv = 127.0f / m;
        int q0 = __float2int_rn(v.x * inv) & 255;
        int q1 = __float2int_rn(v.y * inv) & 255;
        int q2 = __float2int_rn(v.z * inv) & 255;
        int q3 = __float2int_rn(v.w * inv) & 255;
        wq[((size_t)(blk)) * 64 + lane] = q0 | (q1 << 8) | (q2 << 16) | (q3 << 24);
        if (lane == 0) wscale[blk] = m / 127.0f;
    } else {
        int d = blk - 2048;
        src = h0 + (size_t)d * 256;
        float4 v = ((const float4*)src)[lane];
        float m = fmaxf(fmaxf(fabsf(v.x), fabsf(v.y)), fmaxf(fabsf(v.z), fabsf(v.w)));
        #pragma unroll
        for (int off = 1; off < 64; off <<= 1) m = fmaxf(m, __shfl_xor(m, off, 64));
        float inv = 127.0f / m;
        int q0 = __float2int_rn(v.x * inv) & 255;
        int q1 = __float2int_rn(v.y * inv) & 255;
        int q2 = __float2int_rn(v.z * inv) & 255;
        int q3 = __float2int_rn(v.w * inv) & 255;
        hq0[d * 64 + lane] = q0 | (q1 << 8) | (q2 << 16) | (q3 << 24);
        if (lane == 0) sh0[d] = m / 127.0f;
    }
}

// ---------- K1: xg permuted to lstm thread order ----------
// lstm thread tid = m*4+gate reads xg[t*1024 + tid]; row r = gate*256+m.
// Here thread tid=cell computes rows rc*256+tid (rc=gate) -> store float4
// at [t*1024 + tid*4 + rc]: fully coalesced 16B stores.
__global__ __launch_bounds__(256) void xg_kernel(
    const int* __restrict__ sent, const float* __restrict__ embed,
    const float* __restrict__ Wf, const float* __restrict__ bihf, const float* __restrict__ bhhf,
    const float* __restrict__ Wb, const float* __restrict__ bihb, const float* __restrict__ bhhb,
    float* __restrict__ xg)
{
    const int dir = blockIdx.y;
    const int t0 = blockIdx.x * 16;
    const int tid = threadIdx.x;
    const float* W = dir ? Wb : Wf;
    __shared__ float xt[16][256];
    for (int tt = 0; tt < 16; ++tt) {
        int t = t0 + tt;
        int pos = dir ? (S - 1 - t) : t;
        int w = sent[pos];
        xt[tt][tid] = embed[(size_t)w * 256 + tid];
    }
    __syncthreads();
    float acc[4][16];
    #pragma unroll
    for (int rc = 0; rc < 4; ++rc)
        #pragma unroll
        for (int tt = 0; tt < 16; ++tt) acc[rc][tt] = 0.f;
    for (int e = 0; e < 256; ++e) {
        float xv[16];
        #pragma unroll
        for (int tt = 0; tt < 16; ++tt) xv[tt] = xt[tt][e];
        #pragma unroll
        for (int rc = 0; rc < 4; ++rc) {
            float w = W[(size_t)(rc * 256 + tid) * 256 + e];
            #pragma unroll
            for (int tt = 0; tt < 16; ++tt) acc[rc][tt] += w * xv[tt];
        }
    }
    const float* bih = dir ? bihb : bihf;
    const float* bhh = dir ? bhhb : bhhf;
    float b0 = bih[0 * 256 + tid] + bhh[0 * 256 + tid];
    float b1 = bih[1 * 256 + tid] + bhh[1 * 256 + tid];
    float b2 = bih[2 * 256 + tid] + bhh[2 * 256 + tid];
    float b3 = bih[3 * 256 + tid] + bhh[3 * 256 + tid];
    #pragma unroll
    for (int tt = 0; tt < 16; ++tt) {
        float4 v;
        v.x = acc[0][tt] + b0;
        v.y = acc[1][tt] + b1;
        v.z = acc[2][tt] + b2;
        v.w = acc[3][tt] + b3;
        ((float4*)(xg + ((size_t)dir * S + (t0 + tt)) * 1024))[tid] = v;
    }
}

// ---------- K2: sequential LSTM, one block (1024 thr) per direction ----------
// Thread tid: cell m=tid>>2, gate gg=tid&3 (0=i,1=f,2=g,3=o), row r=gg*256+m.
// Weights: 16 NAMED int4 (64 VGPRs) -> guaranteed register-resident (no
// runtime-indexed array => no scratch; R1/R2's VGPR_Count=84 proved spill).
// Gate combine: 3x quad-perm __shfl_xor. One raw s_barrier per step.
#define W_DECL(n) int4 W##n = wp[n];
#define W_DOT(n)  { int4 h4 = hb[n]; \
    a = dot4(W##n.x, h4.x, a); a = dot4(W##n.y, h4.y, a); \
    a = dot4(W##n.z, h4.z, a); a = dot4(W##n.w, h4.w, a); }

__global__ __launch_bounds__(1024, 4) void lstm_kernel(
    const float* __restrict__ xg, const int* __restrict__ wq,
    const float* __restrict__ wscale, const int* __restrict__ hq0,
    const float* __restrict__ sh0, const float* __restrict__ c0,
    float* __restrict__ hs)
{
    const int d = blockIdx.x;
    const int tid = threadIdx.x;
    const int m = tid >> 2;       // cell 0..255
    const int gg = tid & 3;       // gate 0=i,1=f,2=g,3=o
    const int r = gg * 256 + m;   // gate-row

    __shared__ alignas(16) int hqbuf[2][64];

    const int4* wp = (const int4*)(wq + ((size_t)d * 1024 + r) * 64);
    W_DECL(0)  W_DECL(1)  W_DECL(2)  W_DECL(3)
    W_DECL(4)  W_DECL(5)  W_DECL(6)  W_DECL(7)
    W_DECL(8)  W_DECL(9)  W_DECL(10) W_DECL(11)
    W_DECL(12) W_DECL(13) W_DECL(14) W_DECL(15)

    const float s = wscale[d * 1024 + r];
    if (tid < 64) hqbuf[0][tid] = hq0[d * 64 + tid];
    float c = c0[d * 256 + m];            // used on gg==0 lanes
    float sh = sh0[d];
    const float* xgd = xg + (size_t)d * S * 1024;
    float xa = xgd[tid];
    float xb = xgd[1024 + tid];
    float* hsd = hs + (size_t)d * S * 256;
    const float kk = (gg == 2) ? 2.8853900817779268f : -1.4426950408889634f;
    const bool isg = (gg == 2);
    __syncthreads();

    int cur = 0;
    for (int step = 0; step < S; ++step) {
        float xn = 0.f;
        if (step + 2 < S) xn = xgd[(size_t)(step + 2) * 1024 + tid];
        const int4* hb = (const int4*)hqbuf[cur];
        int a = 0;
        W_DOT(0)  W_DOT(1)  W_DOT(2)  W_DOT(3)
        W_DOT(4)  W_DOT(5)  W_DOT(6)  W_DOT(7)
        W_DOT(8)  W_DOT(9)  W_DOT(10) W_DOT(11)
        W_DOT(12) W_DOT(13) W_DOT(14) W_DOT(15)
        float pre = xa + s * sh * (float)a;
        // branchless sigmoid/tanh: both are num * rcp(e+1)
        float xx = fminf(fmaxf(pre, -30.f), 30.f);
        float e = __builtin_amdgcn_exp2f(kk * xx);
        float num = isg ? (e - 1.0f) : 1.0f;
        float act = num * __builtin_amdgcn_rcpf(e + 1.0f);
        float v1 = __shfl_xor(act, 1, 64);   // lane0: f
        float v2 = __shfl_xor(act, 2, 64);   // lane0: g
        float v3 = __shfl_xor(v1, 2, 64);    // lane0: o
        if (gg == 0) {
            c = v1 * c + act * v2;
            float h = v3 * fast_tanh(c);
            hsd[(size_t)step * 256 + m] = h;
            ((signed char*)hqbuf[cur ^ 1])[m] = (signed char)__float2int_rn(h * 127.0f);
        }
        sh = 1.0f / 127.0f;
        xa = xb; xb = xn;
        // make LDS h-write visible; do NOT drain vmcnt (xg prefetch lives on)
        asm volatile("s_waitcnt lgkmcnt(0)" ::: "memory");
        __builtin_amdgcn_s_barrier();
        __builtin_amdgcn_sched_barrier(0);
        cur ^= 1;
    }
}

// ---------- K3: feats[t][tag] = b_out[tag] + W_out[tag] . [hf[t], hb[t]] ----------
__global__ __launch_bounds__(256) void feats_kernel(
    const float* __restrict__ hs, const float* __restrict__ Wout,
    const float* __restrict__ bout, float* __restrict__ feats)
{
    __shared__ float Wl[16][513];
    int tid = threadIdx.x;
    for (int i = tid; i < 16 * 512; i += 256) Wl[i >> 9][i & 511] = Wout[i];
    __syncthreads();
    int tt = tid >> 4, tag = tid & 15;
    int tcur = blockIdx.x * 16 + tt;
    const float* hf = hs + (size_t)tcur * 256;
    const float* hb = hs + (size_t)S * 256 + (size_t)(S - 1 - tcur) * 256;
    float acc = bout[tag];
    for (int k = 0; k < 256; ++k) acc += Wl[tag][k] * hf[k];
    for (int k = 0; k < 256; ++k) acc += Wl[tag][256 + k] * hb[k];
    feats[(size_t)tcur * 16 + tag] = acc;
}

// ---------- K4a: CRF chunk products in log semiring ----------
__global__ __launch_bounds__(256) void crf_chunk_kernel(
    const float* __restrict__ feats, const float* __restrict__ trans,
    float* __restrict__ P)
{
    int chunk = blockIdx.x;
    int tid = threadIdx.x;
    int i = tid >> 4, jj = tid & 15;
    __shared__ float Mt[2][16][17];   // Mt[buf][j][k] = M[k][j]
    float tr[16];
    #pragma unroll
    for (int k = 0; k < 16; ++k) tr[k] = trans[i * 16 + k];
    int t0 = chunk * 64;
    float emit = feats[(size_t)t0 * 16 + i];
    Mt[0][jj][i] = tr[jj] + emit;     // init M = A_{t0}
    __syncthreads();
    int cur = 0;
    float em_next = feats[(size_t)(t0 + 1) * 16 + i];
    for (int s = 1; s < 64; ++s) {
        float em = em_next;
        if (s + 1 < 64) em_next = feats[(size_t)(t0 + s + 1) * 16 + i];
        float v[16];
        #pragma unroll
        for (int k = 0; k < 16; ++k) v[k] = tr[k] + Mt[cur][jj][k];
        float m = v[0];
        #pragma unroll
        for (int k = 1; k < 16; ++k) m = fmaxf(m, v[k]);
        float ssum = 0.f;
        #pragma unroll
        for (int k = 0; k < 16; ++k) ssum += fast_exp(v[k] - m);
        float nv = em + m + fast_log(ssum);
        Mt[cur ^ 1][jj][i] = nv;
        cur ^= 1;
        __syncthreads();
    }
    P[((size_t)chunk * 16 + i) * 16 + jj] = Mt[cur][jj][i];
}

// ---------- K4b: fold 64 chunk matrices through alpha ----------
__global__ __launch_bounds__(256) void crf_fold_kernel(
    const float* __restrict__ P, const float* __restrict__ trans,
    float* __restrict__ out)
{
    int tid = threadIdx.x;
    int i = tid >> 4, jj = tid & 15;
    __shared__ float alpha[16];
    if (tid < 16) alpha[tid] = (tid == START_) ? 0.0f : NEG_;
    __syncthreads();
    for (int cc = 0; cc < 64; ++cc) {
        float pv = P[((size_t)cc * 16 + i) * 16 + jj];
        float v = pv + alpha[jj];
        float m = v;
        #pragma unroll
        for (int off = 1; off < 16; off <<= 1) m = fmaxf(m, __shfl_xor(m, off, 64));
        float e = fast_exp(v - m);
        #pragma unroll
        for (int off = 1; off < 16; off <<= 1) e += __shfl_xor(e, off, 64);
        float nv = m + fast_log(e);
        __syncthreads();
        if (jj == 0) alpha[i] = nv;
        __syncthreads();
    }
    if (tid < 16) {
        float v = alpha[tid] + trans[STOP_ * 16 + tid];
        float m = v;
        #pragma unroll
        for (int off = 1; off < 16; off <<= 1) m = fmaxf(m, __shfl_xor(m, off, 64));
        float e = fast_exp(v - m);
        #pragma unroll
        for (int off = 1; off < 16; off <<= 1) e += __shfl_xor(e, off, 64);
        if (tid == 0) out[0] = m + fast_log(e);
    }
}

extern "C" void kernel_launch(void* const* d_in, const int* in_sizes, int n_in,
                              void* d_out, int out_size, void* d_ws, size_t ws_size,
                              hipStream_t stream) {
    const int*   sent  = (const int*)d_in[0];
    const float* embed = (const float*)d_in[1];
    const float* Wihf  = (const float*)d_in[2];
    const float* Whhf  = (const float*)d_in[3];
    const float* bihf  = (const float*)d_in[4];
    const float* bhhf  = (const float*)d_in[5];
    const float* Wihb  = (const float*)d_in[6];
    const float* Whhb  = (const float*)d_in[7];
    const float* bihb  = (const float*)d_in[8];
    const float* bhhb  = (const float*)d_in[9];
    const float* Wout  = (const float*)d_in[10];
    const float* bout  = (const float*)d_in[11];
    const float* trans = (const float*)d_in[12];
    const float* h0    = (const float*)d_in[13];
    const float* c0    = (const float*)d_in[14];
    float* out = (float*)d_out;

    char* ws = (char*)d_ws;
    constexpr size_t OFF_XG     = 0;                               // 2*S*1024*4 = 32MB
    constexpr size_t OFF_WQ     = OFF_XG + (size_t)2 * S * 1024 * 4;      // 512KB
    constexpr size_t OFF_WSCALE = OFF_WQ + (size_t)2 * 1024 * 64 * 4;     // 8KB
    constexpr size_t OFF_HQ0    = OFF_WSCALE + 2 * 1024 * 4;              // 512B
    constexpr size_t OFF_SH0    = OFF_HQ0 + 2 * 64 * 4;                   // 256B pad
    constexpr size_t OFF_HS     = OFF_SH0 + 256;                          // 8MB
    constexpr size_t OFF_FEATS  = OFF_HS + (size_t)2 * S * 256 * 4;       // 256KB
    constexpr size_t OFF_P      = OFF_FEATS + (size_t)S * 16 * 4;         // 64KB

    float* xg     = (float*)(ws + OFF_XG);
    int*   wq     = (int*)(ws + OFF_WQ);
    float* wscale = (float*)(ws + OFF_WSCALE);
    int*   hq0    = (int*)(ws + OFF_HQ0);
    float* sh0    = (float*)(ws + OFF_SH0);
    float* hs     = (float*)(ws + OFF_HS);
    float* feats  = (float*)(ws + OFF_FEATS);
    float* P      = (float*)(ws + OFF_P);

    quant_kernel<<<dim3(2050), dim3(64), 0, stream>>>(Whhf, Whhb, h0, wq, wscale, hq0, sh0);
    xg_kernel<<<dim3(256, 2), dim3(256), 0, stream>>>(sent, embed, Wihf, bihf, bhhf,
                                                      Wihb, bihb, bhhb, xg);
    lstm_kernel<<<dim3(2), dim3(1024), 0, stream>>>(xg, wq, wscale, hq0, sh0, c0, hs);
    feats_kernel<<<dim3(256), dim3(256), 0, stream>>>(hs, Wout, bout, feats);
    crf_chunk_kernel<<<dim3(64), dim3(256), 0, stream>>>(feats, trans, P);
    crf_fold_kernel<<<dim3(1), dim3(256), 0, stream>>>(P, trans, out);
}

// Round 4
// 3856.923 us; speedup vs baseline: 1.1201x; 1.1201x over previous
//
#include <hip/hip_runtime.h>
#include <hip/hip_bf16.h>

#define S 4096
#define E 256
#define HH 256
#define G4 1024
#define TT 16
#define NEG_ -10000.0f
#define START_ 14
#define STOP_ 15

// ---------- fast math helpers ----------
__device__ __forceinline__ float fast_exp(float x) {           // e^x
    return __builtin_amdgcn_exp2f(x * 1.4426950408889634f);
}
__device__ __forceinline__ float fast_sigmoid(float x) {
    float e = __builtin_amdgcn_exp2f(-1.4426950408889634f * x);
    return __builtin_amdgcn_rcpf(1.0f + e);
}
__device__ __forceinline__ float fast_tanh(float x) {
    float xx = fminf(fmaxf(x, -30.f), 30.f);
    float e = __builtin_amdgcn_exp2f(2.8853900817779268f * xx); // e^{2x}
    return (e - 1.0f) * __builtin_amdgcn_rcpf(e + 1.0f);
}
__device__ __forceinline__ float fast_log(float x) {           // ln
    return 0.6931471805599453f * __builtin_amdgcn_logf(x);
}

#if __has_builtin(__builtin_amdgcn_sdot4)
__device__ __forceinline__ int dot4(int a, int b, int c) {
    return __builtin_amdgcn_sdot4(a, b, c, false);
}
#else
__device__ __forceinline__ int dot4(int a, int b, int c) {
    int d;
    asm("v_dot4_i32_i8 %0, %1, %2, %3" : "=v"(d) : "v"(a), "v"(b), "v"(c));
    return d;
}
#endif

// ---------- K0: quantize W_hh (per-row int8) and h0 ----------
__global__ __launch_bounds__(64) void quant_kernel(
    const float* __restrict__ Wf, const float* __restrict__ Wb,
    const float* __restrict__ h0,
    int* __restrict__ wq, float* __restrict__ wscale,
    int* __restrict__ hq0, float* __restrict__ sh0)
{
    int blk = blockIdx.x, lane = threadIdx.x;  // 64 threads = 1 wave
    const float* src;
    if (blk < 2048) {
        int d = blk >> 10, r = blk & 1023;
        src = (d == 0 ? Wf : Wb) + (size_t)r * 256;
        float4 v = ((const float4*)src)[lane];
        float m = fmaxf(fmaxf(fabsf(v.x), fabsf(v.y)), fmaxf(fabsf(v.z), fabsf(v.w)));
        #pragma unroll
        for (int off = 1; off < 64; off <<= 1) m = fmaxf(m, __shfl_xor(m, off, 64));
        float inv = 127.0f / m;
        int q0 = __float2int_rn(v.x * inv) & 255;
        int q1 = __float2int_rn(v.y * inv) & 255;
        int q2 = __float2int_rn(v.z * inv) & 255;
        int q3 = __float2int_rn(v.w * inv) & 255;
        wq[((size_t)(blk)) * 64 + lane] = q0 | (q1 << 8) | (q2 << 16) | (q3 << 24);
        if (lane == 0) wscale[blk] = m / 127.0f;
    } else {
        int d = blk - 2048;
        src = h0 + (size_t)d * 256;
        float4 v = ((const float4*)src)[lane];
        float m = fmaxf(fmaxf(fabsf(v.x), fabsf(v.y)), fmaxf(fabsf(v.z), fabsf(v.w)));
        #pragma unroll
        for (int off = 1; off < 64; off <<= 1) m = fmaxf(m, __shfl_xor(m, off, 64));
        float inv = 127.0f / m;
        int q0 = __float2int_rn(v.x * inv) & 255;
        int q1 = __float2int_rn(v.y * inv) & 255;
        int q2 = __float2int_rn(v.z * inv) & 255;
        int q3 = __float2int_rn(v.w * inv) & 255;
        hq0[d * 64 + lane] = q0 | (q1 << 8) | (q2 << 16) | (q3 << 24);
        if (lane == 0) sh0[d] = m / 127.0f;
    }
}

// ---------- K1: xg packed per lane-pair ----------
// lstm thread t reads float2 at [step*512 + t]:
//   even t=2m:   (.x,.y) = rows (m, 256+m)      = (i,f)
//   odd  t=2m+1: (.x,.y) = rows (512+m, 768+m)  = (g,o)
// xg_kernel thread tid (cell) stores float4 {i,f,g,o} at index tid.
__global__ __launch_bounds__(256) void xg_kernel(
    const int* __restrict__ sent, const float* __restrict__ embed,
    const float* __restrict__ Wf, const float* __restrict__ bihf, const float* __restrict__ bhhf,
    const float* __restrict__ Wb, const float* __restrict__ bihb, const float* __restrict__ bhhb,
    float* __restrict__ xg)
{
    const int dir = blockIdx.y;
    const int t0 = blockIdx.x * 16;
    const int tid = threadIdx.x;
    const float* W = dir ? Wb : Wf;
    __shared__ float xt[16][256];
    for (int tt = 0; tt < 16; ++tt) {
        int t = t0 + tt;
        int pos = dir ? (S - 1 - t) : t;
        int w = sent[pos];
        xt[tt][tid] = embed[(size_t)w * 256 + tid];
    }
    __syncthreads();
    float acc[4][16];
    #pragma unroll
    for (int rc = 0; rc < 4; ++rc)
        #pragma unroll
        for (int tt = 0; tt < 16; ++tt) acc[rc][tt] = 0.f;
    for (int e = 0; e < 256; ++e) {
        float xv[16];
        #pragma unroll
        for (int tt = 0; tt < 16; ++tt) xv[tt] = xt[tt][e];
        #pragma unroll
        for (int rc = 0; rc < 4; ++rc) {
            float w = W[(size_t)(rc * 256 + tid) * 256 + e];
            #pragma unroll
            for (int tt = 0; tt < 16; ++tt) acc[rc][tt] += w * xv[tt];
        }
    }
    const float* bih = dir ? bihb : bihf;
    const float* bhh = dir ? bhhb : bhhf;
    float b0 = bih[0 * 256 + tid] + bhh[0 * 256 + tid];
    float b1 = bih[1 * 256 + tid] + bhh[1 * 256 + tid];
    float b2 = bih[2 * 256 + tid] + bhh[2 * 256 + tid];
    float b3 = bih[3 * 256 + tid] + bhh[3 * 256 + tid];
    #pragma unroll
    for (int tt = 0; tt < 16; ++tt) {
        float4 v;
        v.x = acc[0][tt] + b0;
        v.y = acc[1][tt] + b1;
        v.z = acc[2][tt] + b2;
        v.w = acc[3][tt] + b3;
        ((float4*)(xg + ((size_t)dir * S + (t0 + tt)) * 1024))[tid] = v;
    }
}

// ---------- K2: sequential LSTM, one block (512 thr) per direction ----------
// Lane pair owns cell m=t>>1: even lane rows {m, 256+m} (i,f),
// odd lane rows {512+m, 768+m} (g,o). 32 NAMED int4 weights, each pinned
// with asm "+v" so they are NOT rematerializable (R3: VGPR=52 proved the
// occupancy heuristic re-loaded weights per step; pinning forces residency).
#define W_DECL(n) int4 Wa##n = wpa[n]; int4 Wb##n = wpb[n]; \
    asm volatile("" : "+v"(Wa##n.x), "+v"(Wa##n.y), "+v"(Wa##n.z), "+v"(Wa##n.w), \
                      "+v"(Wb##n.x), "+v"(Wb##n.y), "+v"(Wb##n.z), "+v"(Wb##n.w));
#define W_DOT(n)  { int4 h4 = hb[n]; \
    a1 = dot4(Wa##n.x, h4.x, a1); a2 = dot4(Wb##n.x, h4.x, a2); \
    a1 = dot4(Wa##n.y, h4.y, a1); a2 = dot4(Wb##n.y, h4.y, a2); \
    a1 = dot4(Wa##n.z, h4.z, a1); a2 = dot4(Wb##n.z, h4.z, a2); \
    a1 = dot4(Wa##n.w, h4.w, a1); a2 = dot4(Wb##n.w, h4.w, a2); }

__global__ __launch_bounds__(512, 2) void lstm_kernel(
    const float* __restrict__ xg, const int* __restrict__ wq,
    const float* __restrict__ wscale, const int* __restrict__ hq0,
    const float* __restrict__ sh0, const float* __restrict__ c0,
    float* __restrict__ hs)
{
    const int d = blockIdx.x;
    const int t = threadIdx.x;
    const int m = t >> 1;          // cell 0..255
    const int odd = t & 1;
    const int r1 = odd * 512 + m;  // i (even) / g (odd)
    const int r2 = r1 + 256;       // f (even) / o (odd)

    __shared__ alignas(16) int hqbuf[2][64];

    const int4* wpa = (const int4*)(wq + ((size_t)d * 1024 + r1) * 64);
    const int4* wpb = (const int4*)(wq + ((size_t)d * 1024 + r2) * 64);
    W_DECL(0)  W_DECL(1)  W_DECL(2)  W_DECL(3)
    W_DECL(4)  W_DECL(5)  W_DECL(6)  W_DECL(7)
    W_DECL(8)  W_DECL(9)  W_DECL(10) W_DECL(11)
    W_DECL(12) W_DECL(13) W_DECL(14) W_DECL(15)

    const float s1 = wscale[d * 1024 + r1];
    const float s2 = wscale[d * 1024 + r2];
    if (t < 64) hqbuf[0][t] = hq0[d * 64 + t];
    float c = c0[d * 256 + m];        // meaningful on even lanes
    float sh = sh0[d];
    const float2* xg2 = (const float2*)(xg + (size_t)d * S * 1024);
    float2 xa = xg2[t];
    float2 xb = xg2[512 + t];
    float* hsd = hs + (size_t)d * S * 256;
    // even: act1 = sigmoid (i), odd: act1 = tanh (g); act2 = sigmoid (f / o)
    const float kk1 = odd ? 2.8853900817779268f : -1.4426950408889634f;
    __syncthreads();

    int cur = 0;
    for (int step = 0; step < S; ++step) {
        float2 xn = make_float2(0.f, 0.f);
        if (step + 2 < S) xn = xg2[(size_t)(step + 2) * 512 + t];
        const int4* hb = (const int4*)hqbuf[cur];
        int a1 = 0, a2 = 0;
        W_DOT(0)  W_DOT(1)  W_DOT(2)  W_DOT(3)
        W_DOT(4)  W_DOT(5)  W_DOT(6)  W_DOT(7)
        W_DOT(8)  W_DOT(9)  W_DOT(10) W_DOT(11)
        W_DOT(12) W_DOT(13) W_DOT(14) W_DOT(15)
        float p1 = xa.x + s1 * sh * (float)a1;   // even: i-pre | odd: g-pre
        float p2 = xa.y + s2 * sh * (float)a2;   // even: f-pre | odd: o-pre
        float x1 = fminf(fmaxf(p1, -30.f), 30.f);
        float e1 = __builtin_amdgcn_exp2f(kk1 * x1);
        float n1 = odd ? (e1 - 1.0f) : 1.0f;
        float act1 = n1 * __builtin_amdgcn_rcpf(e1 + 1.0f);   // even: i | odd: g
        float act2 = fast_sigmoid(p2);                         // even: f | odd: o
        float g = __shfl_xor(act1, 1, 64);   // even receives g
        float o = __shfl_xor(act2, 1, 64);   // even receives o
        if (!odd) {
            c = act2 * c + act1 * g;
            float h = o * fast_tanh(c);
            hsd[(size_t)step * 256 + m] = h;
            ((signed char*)hqbuf[cur ^ 1])[m] = (signed char)__float2int_rn(h * 127.0f);
        }
        sh = 1.0f / 127.0f;
        xa = xb; xb = xn;
        // make LDS h-write visible; do NOT drain vmcnt (xg prefetch lives on)
        asm volatile("s_waitcnt lgkmcnt(0)" ::: "memory");
        __builtin_amdgcn_s_barrier();
        __builtin_amdgcn_sched_barrier(0);
        cur ^= 1;
    }
}

// ---------- K3: feats[t][tag] = b_out[tag] + W_out[tag] . [hf[t], hb[t]] ----------
__global__ __launch_bounds__(256) void feats_kernel(
    const float* __restrict__ hs, const float* __restrict__ Wout,
    const float* __restrict__ bout, float* __restrict__ feats)
{
    __shared__ float Wl[16][513];
    int tid = threadIdx.x;
    for (int i = tid; i < 16 * 512; i += 256) Wl[i >> 9][i & 511] = Wout[i];
    __syncthreads();
    int tt = tid >> 4, tag = tid & 15;
    int tcur = blockIdx.x * 16 + tt;
    const float* hf = hs + (size_t)tcur * 256;
    const float* hb = hs + (size_t)S * 256 + (size_t)(S - 1 - tcur) * 256;
    float acc = bout[tag];
    for (int k = 0; k < 256; ++k) acc += Wl[tag][k] * hf[k];
    for (int k = 0; k < 256; ++k) acc += Wl[tag][256 + k] * hb[k];
    feats[(size_t)tcur * 16 + tag] = acc;
}

// ---------- K4a: CRF chunk products in log semiring ----------
__global__ __launch_bounds__(256) void crf_chunk_kernel(
    const float* __restrict__ feats, const float* __restrict__ trans,
    float* __restrict__ P)
{
    int chunk = blockIdx.x;
    int tid = threadIdx.x;
    int i = tid >> 4, jj = tid & 15;
    __shared__ float Mt[2][16][17];   // Mt[buf][j][k] = M[k][j]
    float tr[16];
    #pragma unroll
    for (int k = 0; k < 16; ++k) tr[k] = trans[i * 16 + k];
    int t0 = chunk * 64;
    float emit = feats[(size_t)t0 * 16 + i];
    Mt[0][jj][i] = tr[jj] + emit;     // init M = A_{t0}
    __syncthreads();
    int cur = 0;
    float em_next = feats[(size_t)(t0 + 1) * 16 + i];
    for (int s = 1; s < 64; ++s) {
        float em = em_next;
        if (s + 1 < 64) em_next = feats[(size_t)(t0 + s + 1) * 16 + i];
        float v[16];
        #pragma unroll
        for (int k = 0; k < 16; ++k) v[k] = tr[k] + Mt[cur][jj][k];
        float m = v[0];
        #pragma unroll
        for (int k = 1; k < 16; ++k) m = fmaxf(m, v[k]);
        float ssum = 0.f;
        #pragma unroll
        for (int k = 0; k < 16; ++k) ssum += fast_exp(v[k] - m);
        float nv = em + m + fast_log(ssum);
        Mt[cur ^ 1][jj][i] = nv;
        cur ^= 1;
        __syncthreads();
    }
    P[((size_t)chunk * 16 + i) * 16 + jj] = Mt[cur][jj][i];
}

// ---------- K4b: fold 64 chunk matrices through alpha ----------
__global__ __launch_bounds__(256) void crf_fold_kernel(
    const float* __restrict__ P, const float* __restrict__ trans,
    float* __restrict__ out)
{
    int tid = threadIdx.x;
    int i = tid >> 4, jj = tid & 15;
    __shared__ float alpha[16];
    if (tid < 16) alpha[tid] = (tid == START_) ? 0.0f : NEG_;
    __syncthreads();
    for (int cc = 0; cc < 64; ++cc) {
        float pv = P[((size_t)cc * 16 + i) * 16 + jj];
        float v = pv + alpha[jj];
        float m = v;
        #pragma unroll
        for (int off = 1; off < 16; off <<= 1) m = fmaxf(m, __shfl_xor(m, off, 64));
        float e = fast_exp(v - m);
        #pragma unroll
        for (int off = 1; off < 16; off <<= 1) e += __shfl_xor(e, off, 64);
        float nv = m + fast_log(e);
        __syncthreads();
        if (jj == 0) alpha[i] = nv;
        __syncthreads();
    }
    if (tid < 16) {
        float v = alpha[tid] + trans[STOP_ * 16 + tid];
        float m = v;
        #pragma unroll
        for (int off = 1; off < 16; off <<= 1) m = fmaxf(m, __shfl_xor(m, off, 64));
        float e = fast_exp(v - m);
        #pragma unroll
        for (int off = 1; off < 16; off <<= 1) e += __shfl_xor(e, off, 64);
        if (tid == 0) out[0] = m + fast_log(e);
    }
}

extern "C" void kernel_launch(void* const* d_in, const int* in_sizes, int n_in,
                              void* d_out, int out_size, void* d_ws, size_t ws_size,
                              hipStream_t stream) {
    const int*   sent  = (const int*)d_in[0];
    const float* embed = (const float*)d_in[1];
    const float* Wihf  = (const float*)d_in[2];
    const float* Whhf  = (const float*)d_in[3];
    const float* bihf  = (const float*)d_in[4];
    const float* bhhf  = (const float*)d_in[5];
    const float* Wihb  = (const float*)d_in[6];
    const float* Whhb  = (const float*)d_in[7];
    const float* bihb  = (const float*)d_in[8];
    const float* bhhb  = (const float*)d_in[9];
    const float* Wout  = (const float*)d_in[10];
    const float* bout  = (const float*)d_in[11];
    const float* trans = (const float*)d_in[12];
    const float* h0    = (const float*)d_in[13];
    const float* c0    = (const float*)d_in[14];
    float* out = (float*)d_out;

    char* ws = (char*)d_ws;
    constexpr size_t OFF_XG     = 0;                               // 2*S*1024*4 = 32MB
    constexpr size_t OFF_WQ     = OFF_XG + (size_t)2 * S * 1024 * 4;      // 512KB
    constexpr size_t OFF_WSCALE = OFF_WQ + (size_t)2 * 1024 * 64 * 4;     // 8KB
    constexpr size_t OFF_HQ0    = OFF_WSCALE + 2 * 1024 * 4;              // 512B
    constexpr size_t OFF_SH0    = OFF_HQ0 + 2 * 64 * 4;                   // 256B pad
    constexpr size_t OFF_HS     = OFF_SH0 + 256;                          // 8MB
    constexpr size_t OFF_FEATS  = OFF_HS + (size_t)2 * S * 256 * 4;       // 256KB
    constexpr size_t OFF_P      = OFF_FEATS + (size_t)S * 16 * 4;         // 64KB

    float* xg     = (float*)(ws + OFF_XG);
    int*   wq     = (int*)(ws + OFF_WQ);
    float* wscale = (float*)(ws + OFF_WSCALE);
    int*   hq0    = (int*)(ws + OFF_HQ0);
    float* sh0    = (float*)(ws + OFF_SH0);
    float* hs     = (float*)(ws + OFF_HS);
    float* feats  = (float*)(ws + OFF_FEATS);
    float* P      = (float*)(ws + OFF_P);

    quant_kernel<<<dim3(2050), dim3(64), 0, stream>>>(Whhf, Whhb, h0, wq, wscale, hq0, sh0);
    xg_kernel<<<dim3(256, 2), dim3(256), 0, stream>>>(sent, embed, Wihf, bihf, bhhf,
                                                      Wihb, bihb, bhhb, xg);
    lstm_kernel<<<dim3(2), dim3(512), 0, stream>>>(xg, wq, wscale, hq0, sh0, c0, hs);
    feats_kernel<<<dim3(256), dim3(256), 0, stream>>>(hs, Wout, bout, feats);
    crf_chunk_kernel<<<dim3(64), dim3(256), 0, stream>>>(feats, trans, P);
    crf_fold_kernel<<<dim3(1), dim3(256), 0, stream>>>(P, trans, out);
}

// Round 5
// 3760.069 us; speedup vs baseline: 1.1490x; 1.0258x over previous
//
#include <hip/hip_runtime.h>
#include <hip/hip_bf16.h>

#define S 4096
#define E 256
#define HH 256
#define TT 16
#define NEG_ -10000.0f
#define START_ 14
#define STOP_ 15

// ---------- fast math helpers (host-side kernels) ----------
__device__ __forceinline__ float fast_exp(float x) {           // e^x
    return __builtin_amdgcn_exp2f(x * 1.4426950408889634f);
}
__device__ __forceinline__ float fast_log(float x) {           // ln
    return 0.6931471805599453f * __builtin_amdgcn_logf(x);
}

// ---------- K0: quantize W_hh (per-row int8) and h0 ----------
__global__ __launch_bounds__(64) void quant_kernel(
    const float* __restrict__ Wf, const float* __restrict__ Wb,
    const float* __restrict__ h0,
    int* __restrict__ wq, float* __restrict__ wscale,
    int* __restrict__ hq0, float* __restrict__ sh0)
{
    int blk = blockIdx.x, lane = threadIdx.x;  // 64 threads = 1 wave
    const float* src;
    if (blk < 2048) {
        int d = blk >> 10, r = blk & 1023;
        src = (d == 0 ? Wf : Wb) + (size_t)r * 256;
        float4 v = ((const float4*)src)[lane];
        float m = fmaxf(fmaxf(fabsf(v.x), fabsf(v.y)), fmaxf(fabsf(v.z), fabsf(v.w)));
        #pragma unroll
        for (int off = 1; off < 64; off <<= 1) m = fmaxf(m, __shfl_xor(m, off, 64));
        float inv = 127.0f / m;
        int q0 = __float2int_rn(v.x * inv) & 255;
        int q1 = __float2int_rn(v.y * inv) & 255;
        int q2 = __float2int_rn(v.z * inv) & 255;
        int q3 = __float2int_rn(v.w * inv) & 255;
        wq[((size_t)(blk)) * 64 + lane] = q0 | (q1 << 8) | (q2 << 16) | (q3 << 24);
        if (lane == 0) wscale[blk] = m / 127.0f;
    } else {
        int d = blk - 2048;
        src = h0 + (size_t)d * 256;
        float4 v = ((const float4*)src)[lane];
        float m = fmaxf(fmaxf(fabsf(v.x), fabsf(v.y)), fmaxf(fabsf(v.z), fabsf(v.w)));
        #pragma unroll
        for (int off = 1; off < 64; off <<= 1) m = fmaxf(m, __shfl_xor(m, off, 64));
        float inv = 127.0f / m;
        int q0 = __float2int_rn(v.x * inv) & 255;
        int q1 = __float2int_rn(v.y * inv) & 255;
        int q2 = __float2int_rn(v.z * inv) & 255;
        int q3 = __float2int_rn(v.w * inv) & 255;
        hq0[d * 64 + lane] = q0 | (q1 << 8) | (q2 << 16) | (q3 << 24);
        if (lane == 0) sh0[d] = m / 127.0f;
    }
}

// ---------- K1: xg packed per lane-pair ----------
// lstm thread t reads float2 at byte [step*4096 + t*8]:
//   even t=2m:   (.x,.y) = rows (m, 256+m)      = (i,f)
//   odd  t=2m+1: (.x,.y) = rows (512+m, 768+m)  = (g,o)
__global__ __launch_bounds__(256) void xg_kernel(
    const int* __restrict__ sent, const float* __restrict__ embed,
    const float* __restrict__ Wf, const float* __restrict__ bihf, const float* __restrict__ bhhf,
    const float* __restrict__ Wb, const float* __restrict__ bihb, const float* __restrict__ bhhb,
    float* __restrict__ xg)
{
    const int dir = blockIdx.y;
    const int t0 = blockIdx.x * 16;
    const int tid = threadIdx.x;
    const float* W = dir ? Wb : Wf;
    __shared__ float xt[16][256];
    for (int tt = 0; tt < 16; ++tt) {
        int t = t0 + tt;
        int pos = dir ? (S - 1 - t) : t;
        int w = sent[pos];
        xt[tt][tid] = embed[(size_t)w * 256 + tid];
    }
    __syncthreads();
    float acc[4][16];
    #pragma unroll
    for (int rc = 0; rc < 4; ++rc)
        #pragma unroll
        for (int tt = 0; tt < 16; ++tt) acc[rc][tt] = 0.f;
    for (int e = 0; e < 256; ++e) {
        float xv[16];
        #pragma unroll
        for (int tt = 0; tt < 16; ++tt) xv[tt] = xt[tt][e];
        #pragma unroll
        for (int rc = 0; rc < 4; ++rc) {
            float w = W[(size_t)(rc * 256 + tid) * 256 + e];
            #pragma unroll
            for (int tt = 0; tt < 16; ++tt) acc[rc][tt] += w * xv[tt];
        }
    }
    const float* bih = dir ? bihb : bihf;
    const float* bhh = dir ? bhhb : bhhf;
    float b0 = bih[0 * 256 + tid] + bhh[0 * 256 + tid];
    float b1 = bih[1 * 256 + tid] + bhh[1 * 256 + tid];
    float b2 = bih[2 * 256 + tid] + bhh[2 * 256 + tid];
    float b3 = bih[3 * 256 + tid] + bhh[3 * 256 + tid];
    #pragma unroll
    for (int tt = 0; tt < 16; ++tt) {
        float4 v;
        v.x = acc[0][tt] + b0;
        v.y = acc[1][tt] + b1;
        v.z = acc[2][tt] + b2;
        v.w = acc[3][tt] + b3;
        ((float4*)(xg + ((size_t)dir * S + (t0 + tt)) * 1024))[tid] = v;
    }
}

// ---------- K2: sequential LSTM, FULL inline-asm inner loop ----------
// Register map (explicit): weights v32-v159 (chunk q: A=v[32+32q..+15],
// B=v[48+32q..+15]); h chunks v160-175 / v176-191; accs v192-195;
// xA v196-197 / xB v198-199; offsets v200-203; temps v204-214; scales v216-217.

#define D4(a,w,h) "v_dot4_i32_i8 " a ", " w ", " h ", " a "\n\t"
#define DPe(wa,wb,h) D4("v192",wa,h) D4("v194",wb,h)
#define DPo(wa,wb,h) D4("v193",wa,h) D4("v195",wb,h)

#define CH0 \
 DPe("v32","v48","v160") DPo("v33","v49","v161") DPe("v34","v50","v162") DPo("v35","v51","v163") \
 DPe("v36","v52","v164") DPo("v37","v53","v165") DPe("v38","v54","v166") DPo("v39","v55","v167") \
 DPe("v40","v56","v168") DPo("v41","v57","v169") DPe("v42","v58","v170") DPo("v43","v59","v171") \
 DPe("v44","v60","v172") DPo("v45","v61","v173") DPe("v46","v62","v174") DPo("v47","v63","v175")

#define CH1 \
 DPe("v64","v80","v176") DPo("v65","v81","v177") DPe("v66","v82","v178") DPo("v67","v83","v179") \
 DPe("v68","v84","v180") DPo("v69","v85","v181") DPe("v70","v86","v182") DPo("v71","v87","v183") \
 DPe("v72","v88","v184") DPo("v73","v89","v185") DPe("v74","v90","v186") DPo("v75","v91","v187") \
 DPe("v76","v92","v188") DPo("v77","v93","v189") DPe("v78","v94","v190") DPo("v79","v95","v191")

#define CH2 \
 DPe("v96","v112","v160") DPo("v97","v113","v161") DPe("v98","v114","v162") DPo("v99","v115","v163") \
 DPe("v100","v116","v164") DPo("v101","v117","v165") DPe("v102","v118","v166") DPo("v103","v119","v167") \
 DPe("v104","v120","v168") DPo("v105","v121","v169") DPe("v106","v122","v170") DPo("v107","v123","v171") \
 DPe("v108","v124","v172") DPo("v109","v125","v173") DPe("v110","v126","v174") DPo("v111","v127","v175")

#define CH3 \
 DPe("v128","v144","v176") DPo("v129","v145","v177") DPe("v130","v146","v178") DPo("v131","v147","v179") \
 DPe("v132","v148","v180") DPo("v133","v149","v181") DPe("v134","v150","v182") DPo("v135","v151","v183") \
 DPe("v136","v152","v184") DPo("v137","v153","v185") DPe("v138","v154","v186") DPo("v139","v155","v187") \
 DPe("v140","v156","v188") DPo("v141","v157","v189") DPe("v142","v158","v190") DPo("v143","v159","v191")

// one LSTM step; XA0/XA1 = regs holding xg[s], BPAIR = dest for xg[s+1] load
#define LSTM_BODY(XA0, XA1, BPAIR) \
  "global_load_dwordx2 " BPAIR ", v200, %[sxg]\n\t" \
  "ds_read_b128 v[160:163], v202\n\t" \
  "ds_read_b128 v[164:167], v202 offset:16\n\t" \
  "ds_read_b128 v[168:171], v202 offset:32\n\t" \
  "ds_read_b128 v[172:175], v202 offset:48\n\t" \
  "ds_read_b128 v[176:179], v202 offset:64\n\t" \
  "ds_read_b128 v[180:183], v202 offset:80\n\t" \
  "ds_read_b128 v[184:187], v202 offset:96\n\t" \
  "ds_read_b128 v[188:191], v202 offset:112\n\t" \
  "v_mov_b32 v192, 0\n\t" \
  "v_mov_b32 v193, 0\n\t" \
  "v_mov_b32 v194, 0\n\t" \
  "v_mov_b32 v195, 0\n\t" \
  "s_waitcnt lgkmcnt(4)\n\t" \
  CH0 \
  "ds_read_b128 v[160:163], v202 offset:128\n\t" \
  "ds_read_b128 v[164:167], v202 offset:144\n\t" \
  "ds_read_b128 v[168:171], v202 offset:160\n\t" \
  "ds_read_b128 v[172:175], v202 offset:176\n\t" \
  "s_waitcnt lgkmcnt(4)\n\t" \
  CH1 \
  "ds_read_b128 v[176:179], v202 offset:192\n\t" \
  "ds_read_b128 v[180:183], v202 offset:208\n\t" \
  "ds_read_b128 v[184:187], v202 offset:224\n\t" \
  "ds_read_b128 v[188:191], v202 offset:240\n\t" \
  "s_waitcnt lgkmcnt(4)\n\t" \
  CH2 \
  "s_waitcnt lgkmcnt(0)\n\t" \
  CH3 \
  "v_add_u32 v192, v192, v193\n\t" \
  "v_add_u32 v194, v194, v195\n\t" \
  "v_cvt_f32_i32 v204, v192\n\t" \
  "v_cvt_f32_i32 v205, v194\n\t" \
  "s_waitcnt vmcnt(1)\n\t" \
  "v_fma_f32 v206, v216, v204, " XA0 "\n\t" \
  "v_fma_f32 v207, v217, v205, " XA1 "\n\t" \
  "v_mov_b32 v216, %[s1f]\n\t" \
  "v_mov_b32 v217, %[s2f]\n\t" \
  "v_med3_f32 v206, v206, %[ncl], %[pcl]\n\t" \
  "v_mul_f32 v204, %[kk1], v206\n\t" \
  "v_mul_f32 v208, %[nk], v207\n\t" \
  "v_exp_f32 v204, v204\n\t" \
  "v_exp_f32 v208, v208\n\t" \
  "s_nop 1\n\t" \
  "v_fma_f32 v205, v204, %[mk], %[bk]\n\t" \
  "v_add_f32 v206, 1.0, v204\n\t" \
  "v_add_f32 v209, 1.0, v208\n\t" \
  "v_rcp_f32 v206, v206\n\t" \
  "v_rcp_f32 v212, v209\n\t" \
  "s_nop 1\n\t" \
  "v_mul_f32 v211, v205, v206\n\t" \
  "ds_swizzle_b32 v209, v211 offset:0x041F\n\t" \
  "ds_swizzle_b32 v210, v212 offset:0x041F\n\t" \
  "s_waitcnt lgkmcnt(0)\n\t" \
  "v_cndmask_b32 v204, v211, v209, %[pm]\n\t" \
  "v_cndmask_b32 v205, v212, v210, %[pm]\n\t" \
  "v_cndmask_b32 v206, v209, v211, %[pm]\n\t" \
  "v_cndmask_b32 v207, v210, v212, %[pm]\n\t" \
  "v_mul_f32 v213, v205, v213\n\t" \
  "v_fmac_f32 v213, v204, v206\n\t" \
  "v_med3_f32 v204, v213, %[ncl], %[pcl]\n\t" \
  "v_mul_f32 v204, %[k2], v204\n\t" \
  "v_exp_f32 v204, v204\n\t" \
  "s_nop 1\n\t" \
  "v_add_f32 v205, -1.0, v204\n\t" \
  "v_add_f32 v206, 1.0, v204\n\t" \
  "v_rcp_f32 v206, v206\n\t" \
  "s_nop 1\n\t" \
  "v_mul_f32 v205, v205, v206\n\t" \
  "v_mul_f32 v214, v207, v205\n\t" \
  "global_store_dword v201, v214, %[shs]\n\t" \
  "v_mul_f32 v204, %[c127], v214\n\t" \
  "v_rndne_f32 v204, v204\n\t" \
  "v_cvt_i32_f32 v204, v204\n\t" \
  "ds_write_b8 v203, v204\n\t" \
  "v_add_u32 v200, 0x1000, v200\n\t" \
  "v_add_u32 v201, 0x400, v201\n\t" \
  "v_xor_b32 v202, 0x100, v202\n\t" \
  "v_xor_b32 v203, 0x100, v203\n\t" \
  "s_waitcnt lgkmcnt(0)\n\t" \
  "s_barrier\n\t"

__global__ __launch_bounds__(512, 2) void lstm_kernel(
    const float* __restrict__ xg, const int* __restrict__ wq,
    const float* __restrict__ wscale, const int* __restrict__ hq0,
    const float* __restrict__ sh0, const float* __restrict__ c0,
    float* __restrict__ hs)
{
    const int d = blockIdx.x;
    const int t = threadIdx.x;
    const int m = t >> 1;          // cell 0..255
    const int odd = t & 1;
    const int r1 = odd * 512 + m;  // i (even) / g (odd)
    const int r2 = r1 + 256;       // f (even) / o (odd)

    __shared__ alignas(16) int hqbuf[2][64];   // sole LDS object -> ds offset 0

    const int*   wq_d = wq + (size_t)d * 65536;
    const float* xg_d = xg + (size_t)d * S * 1024;
    float*       hs_d = hs + (size_t)d * S * 256;
    const float s1 = wscale[d * 1024 + r1];
    const float s2 = wscale[d * 1024 + r2];
    const float sh0v = sh0[d];
    const float c0v = c0[d * 256 + m];
    const int h0v = hq0[d * 64 + (t & 63)];
    const unsigned h0a  = (unsigned)(t & 63) * 4u;
    const unsigned xoff = (unsigned)t * 8u;
    const unsigned hoff = (unsigned)m * 4u;
    const unsigned ldsw = 256u + (unsigned)m;
    const unsigned voA  = (unsigned)r1 * 256u;
    const unsigned voB  = (unsigned)r2 * 256u;
    const float sc1i = s1 * sh0v, sc2i = s2 * sh0v;          // step-0 scales
    const float sc1f = s1 * (1.0f / 127.0f);                 // steady-state
    const float sc2f = s2 * (1.0f / 127.0f);
    const float kk1 = odd ? 2.8853900817779268f : -1.4426950408889634f;
    const float mkv = odd ? 1.0f : 0.0f;
    const float bkv = odd ? -1.0f : 1.0f;
    const float nkv = -1.4426950408889634f;
    const float k2v = 2.8853900817779268f;
    const float c127 = 127.0f;
    const float nclv = -30.0f, pclv = 30.0f;
    const unsigned long long pmask = 0xAAAAAAAAAAAAAAAAULL;  // odd lanes
    const unsigned lds_keep = (unsigned)(size_t)&hqbuf[0][0];
    int cnt = S / 2;   // body unrolled x2

    asm volatile(
        // ---- prologue: init state, h0 -> LDS, weights -> v32..v159 ----
        "v_mov_b32 v200, %[xoff]\n\t"
        "v_mov_b32 v201, %[hoff]\n\t"
        "v_mov_b32 v202, 0\n\t"
        "v_mov_b32 v203, %[ldsw]\n\t"
        "v_mov_b32 v213, %[c0v]\n\t"
        "v_mov_b32 v216, %[s1i]\n\t"
        "v_mov_b32 v217, %[s2i]\n\t"
        "ds_write_b32 %[h0a], %[h0v]\n\t"
        "global_load_dwordx4 v[32:35],   %[voA], %[swq]\n\t"
        "global_load_dwordx4 v[36:39],   %[voA], %[swq] offset:16\n\t"
        "global_load_dwordx4 v[40:43],   %[voA], %[swq] offset:32\n\t"
        "global_load_dwordx4 v[44:47],   %[voA], %[swq] offset:48\n\t"
        "global_load_dwordx4 v[64:67],   %[voA], %[swq] offset:64\n\t"
        "global_load_dwordx4 v[68:71],   %[voA], %[swq] offset:80\n\t"
        "global_load_dwordx4 v[72:75],   %[voA], %[swq] offset:96\n\t"
        "global_load_dwordx4 v[76:79],   %[voA], %[swq] offset:112\n\t"
        "global_load_dwordx4 v[96:99],   %[voA], %[swq] offset:128\n\t"
        "global_load_dwordx4 v[100:103], %[voA], %[swq] offset:144\n\t"
        "global_load_dwordx4 v[104:107], %[voA], %[swq] offset:160\n\t"
        "global_load_dwordx4 v[108:111], %[voA], %[swq] offset:176\n\t"
        "global_load_dwordx4 v[128:131], %[voA], %[swq] offset:192\n\t"
        "global_load_dwordx4 v[132:135], %[voA], %[swq] offset:208\n\t"
        "global_load_dwordx4 v[136:139], %[voA], %[swq] offset:224\n\t"
        "global_load_dwordx4 v[140:143], %[voA], %[swq] offset:240\n\t"
        "global_load_dwordx4 v[48:51],   %[voB], %[swq]\n\t"
        "global_load_dwordx4 v[52:55],   %[voB], %[swq] offset:16\n\t"
        "global_load_dwordx4 v[56:59],   %[voB], %[swq] offset:32\n\t"
        "global_load_dwordx4 v[60:63],   %[voB], %[swq] offset:48\n\t"
        "global_load_dwordx4 v[80:83],   %[voB], %[swq] offset:64\n\t"
        "global_load_dwordx4 v[84:87],   %[voB], %[swq] offset:80\n\t"
        "global_load_dwordx4 v[88:91],   %[voB], %[swq] offset:96\n\t"
        "global_load_dwordx4 v[92:95],   %[voB], %[swq] offset:112\n\t"
        "global_load_dwordx4 v[112:115], %[voB], %[swq] offset:128\n\t"
        "global_load_dwordx4 v[116:119], %[voB], %[swq] offset:144\n\t"
        "global_load_dwordx4 v[120:123], %[voB], %[swq] offset:160\n\t"
        "global_load_dwordx4 v[124:127], %[voB], %[swq] offset:176\n\t"
        "global_load_dwordx4 v[144:147], %[voB], %[swq] offset:192\n\t"
        "global_load_dwordx4 v[148:151], %[voB], %[swq] offset:208\n\t"
        "global_load_dwordx4 v[152:155], %[voB], %[swq] offset:224\n\t"
        "global_load_dwordx4 v[156:159], %[voB], %[swq] offset:240\n\t"
        "global_load_dwordx2 v[196:197], v200, %[sxg]\n\t"
        "v_add_u32 v200, 0x1000, v200\n\t"
        "s_waitcnt vmcnt(0) lgkmcnt(0)\n\t"
        "s_barrier\n\t"
        // ---- main loop: 2 steps per iteration ----
        "Llstm%=:\n\t"
        LSTM_BODY("v196", "v197", "v[198:199]")
        LSTM_BODY("v198", "v199", "v[196:197]")
        "s_add_i32 %[cnt], %[cnt], -1\n\t"
        "s_cmp_lg_u32 %[cnt], 0\n\t"
        "s_cbranch_scc1 Llstm%=\n\t"
        : [cnt] "+s"(cnt)
        : [sxg] "s"(xg_d), [shs] "s"(hs_d), [swq] "s"(wq_d), [pm] "s"(pmask),
          [xoff] "v"(xoff), [hoff] "v"(hoff), [ldsw] "v"(ldsw), [c0v] "v"(c0v),
          [s1i] "v"(sc1i), [s2i] "v"(sc2i), [s1f] "v"(sc1f), [s2f] "v"(sc2f),
          [kk1] "v"(kk1), [mk] "v"(mkv), [bk] "v"(bkv), [nk] "v"(nkv),
          [k2] "v"(k2v), [c127] "v"(c127), [ncl] "v"(nclv), [pcl] "v"(pclv),
          [voA] "v"(voA), [voB] "v"(voB), [h0a] "v"(h0a), [h0v] "v"(h0v),
          [keep] "v"(lds_keep)
        : "memory", "scc",
          "v32","v33","v34","v35","v36","v37","v38","v39",
          "v40","v41","v42","v43","v44","v45","v46","v47",
          "v48","v49","v50","v51","v52","v53","v54","v55",
          "v56","v57","v58","v59","v60","v61","v62","v63",
          "v64","v65","v66","v67","v68","v69","v70","v71",
          "v72","v73","v74","v75","v76","v77","v78","v79",
          "v80","v81","v82","v83","v84","v85","v86","v87",
          "v88","v89","v90","v91","v92","v93","v94","v95",
          "v96","v97","v98","v99","v100","v101","v102","v103",
          "v104","v105","v106","v107","v108","v109","v110","v111",
          "v112","v113","v114","v115","v116","v117","v118","v119",
          "v120","v121","v122","v123","v124","v125","v126","v127",
          "v128","v129","v130","v131","v132","v133","v134","v135",
          "v136","v137","v138","v139","v140","v141","v142","v143",
          "v144","v145","v146","v147","v148","v149","v150","v151",
          "v152","v153","v154","v155","v156","v157","v158","v159",
          "v160","v161","v162","v163","v164","v165","v166","v167",
          "v168","v169","v170","v171","v172","v173","v174","v175",
          "v176","v177","v178","v179","v180","v181","v182","v183",
          "v184","v185","v186","v187","v188","v189","v190","v191",
          "v192","v193","v194","v195","v196","v197","v198","v199",
          "v200","v201","v202","v203","v204","v205","v206","v207",
          "v208","v209","v210","v211","v212","v213","v214","v215",
          "v216","v217");
}

// ---------- K3: feats[t][tag] = b_out[tag] + W_out[tag] . [hf[t], hb[t]] ----------
__global__ __launch_bounds__(256) void feats_kernel(
    const float* __restrict__ hs, const float* __restrict__ Wout,
    const float* __restrict__ bout, float* __restrict__ feats)
{
    __shared__ float Wl[16][513];
    int tid = threadIdx.x;
    for (int i = tid; i < 16 * 512; i += 256) Wl[i >> 9][i & 511] = Wout[i];
    __syncthreads();
    int tt = tid >> 4, tag = tid & 15;
    int tcur = blockIdx.x * 16 + tt;
    const float* hf = hs + (size_t)tcur * 256;
    const float* hb = hs + (size_t)S * 256 + (size_t)(S - 1 - tcur) * 256;
    float acc = bout[tag];
    for (int k = 0; k < 256; ++k) acc += Wl[tag][k] * hf[k];
    for (int k = 0; k < 256; ++k) acc += Wl[tag][256 + k] * hb[k];
    feats[(size_t)tcur * 16 + tag] = acc;
}

// ---------- K4a: CRF chunk products in log semiring ----------
__global__ __launch_bounds__(256) void crf_chunk_kernel(
    const float* __restrict__ feats, const float* __restrict__ trans,
    float* __restrict__ P)
{
    int chunk = blockIdx.x;
    int tid = threadIdx.x;
    int i = tid >> 4, jj = tid & 15;
    __shared__ float Mt[2][16][17];   // Mt[buf][j][k] = M[k][j]
    float tr[16];
    #pragma unroll
    for (int k = 0; k < 16; ++k) tr[k] = trans[i * 16 + k];
    int t0 = chunk * 64;
    float emit = feats[(size_t)t0 * 16 + i];
    Mt[0][jj][i] = tr[jj] + emit;     // init M = A_{t0}
    __syncthreads();
    int cur = 0;
    float em_next = feats[(size_t)(t0 + 1) * 16 + i];
    for (int s = 1; s < 64; ++s) {
        float em = em_next;
        if (s + 1 < 64) em_next = feats[(size_t)(t0 + s + 1) * 16 + i];
        float v[16];
        #pragma unroll
        for (int k = 0; k < 16; ++k) v[k] = tr[k] + Mt[cur][jj][k];
        float m = v[0];
        #pragma unroll
        for (int k = 1; k < 16; ++k) m = fmaxf(m, v[k]);
        float ssum = 0.f;
        #pragma unroll
        for (int k = 0; k < 16; ++k) ssum += fast_exp(v[k] - m);
        float nv = em + m + fast_log(ssum);
        Mt[cur ^ 1][jj][i] = nv;
        cur ^= 1;
        __syncthreads();
    }
    P[((size_t)chunk * 16 + i) * 16 + jj] = Mt[cur][jj][i];
}

// ---------- K4b: fold 64 chunk matrices through alpha ----------
__global__ __launch_bounds__(256) void crf_fold_kernel(
    const float* __restrict__ P, const float* __restrict__ trans,
    float* __restrict__ out)
{
    int tid = threadIdx.x;
    int i = tid >> 4, jj = tid & 15;
    __shared__ float alpha[16];
    if (tid < 16) alpha[tid] = (tid == START_) ? 0.0f : NEG_;
    __syncthreads();
    for (int cc = 0; cc < 64; ++cc) {
        float pv = P[((size_t)cc * 16 + i) * 16 + jj];
        float v = pv + alpha[jj];
        float m = v;
        #pragma unroll
        for (int off = 1; off < 16; off <<= 1) m = fmaxf(m, __shfl_xor(m, off, 64));
        float e = fast_exp(v - m);
        #pragma unroll
        for (int off = 1; off < 16; off <<= 1) e += __shfl_xor(e, off, 64);
        float nv = m + fast_log(e);
        __syncthreads();
        if (jj == 0) alpha[i] = nv;
        __syncthreads();
    }
    if (tid < 16) {
        float v = alpha[tid] + trans[STOP_ * 16 + tid];
        float m = v;
        #pragma unroll
        for (int off = 1; off < 16; off <<= 1) m = fmaxf(m, __shfl_xor(m, off, 64));
        float e = fast_exp(v - m);
        #pragma unroll
        for (int off = 1; off < 16; off <<= 1) e += __shfl_xor(e, off, 64);
        if (tid == 0) out[0] = m + fast_log(e);
    }
}

extern "C" void kernel_launch(void* const* d_in, const int* in_sizes, int n_in,
                              void* d_out, int out_size, void* d_ws, size_t ws_size,
                              hipStream_t stream) {
    const int*   sent  = (const int*)d_in[0];
    const float* embed = (const float*)d_in[1];
    const float* Wihf  = (const float*)d_in[2];
    const float* Whhf  = (const float*)d_in[3];
    const float* bihf  = (const float*)d_in[4];
    const float* bhhf  = (const float*)d_in[5];
    const float* Wihb  = (const float*)d_in[6];
    const float* Whhb  = (const float*)d_in[7];
    const float* bihb  = (const float*)d_in[8];
    const float* bhhb  = (const float*)d_in[9];
    const float* Wout  = (const float*)d_in[10];
    const float* bout  = (const float*)d_in[11];
    const float* trans = (const float*)d_in[12];
    const float* h0    = (const float*)d_in[13];
    const float* c0    = (const float*)d_in[14];
    float* out = (float*)d_out;

    char* ws = (char*)d_ws;
    constexpr size_t OFF_XG     = 0;                                      // 32MB
    constexpr size_t OFF_WQ     = OFF_XG + (size_t)2 * S * 1024 * 4;      // 512KB
    constexpr size_t OFF_WSCALE = OFF_WQ + (size_t)2 * 1024 * 64 * 4;     // 8KB
    constexpr size_t OFF_HQ0    = OFF_WSCALE + 2 * 1024 * 4;              // 512B
    constexpr size_t OFF_SH0    = OFF_HQ0 + 2 * 64 * 4;                   // 256B pad
    constexpr size_t OFF_HS     = OFF_SH0 + 256;                          // 8MB
    constexpr size_t OFF_FEATS  = OFF_HS + (size_t)2 * S * 256 * 4;       // 256KB
    constexpr size_t OFF_P      = OFF_FEATS + (size_t)S * 16 * 4;         // 64KB

    float* xg     = (float*)(ws + OFF_XG);
    int*   wq     = (int*)(ws + OFF_WQ);
    float* wscale = (float*)(ws + OFF_WSCALE);
    int*   hq0    = (int*)(ws + OFF_HQ0);
    float* sh0    = (float*)(ws + OFF_SH0);
    float* hs     = (float*)(ws + OFF_HS);
    float* feats  = (float*)(ws + OFF_FEATS);
    float* P      = (float*)(ws + OFF_P);

    quant_kernel<<<dim3(2050), dim3(64), 0, stream>>>(Whhf, Whhb, h0, wq, wscale, hq0, sh0);
    xg_kernel<<<dim3(256, 2), dim3(256), 0, stream>>>(sent, embed, Wihf, bihf, bhhf,
                                                      Wihb, bihb, bhhb, xg);
    lstm_kernel<<<dim3(2), dim3(512), 0, stream>>>(xg, wq, wscale, hq0, sh0, c0, hs);
    feats_kernel<<<dim3(256), dim3(256), 0, stream>>>(hs, Wout, bout, feats);
    crf_chunk_kernel<<<dim3(64), dim3(256), 0, stream>>>(feats, trans, P);
    crf_fold_kernel<<<dim3(1), dim3(256), 0, stream>>>(P, trans, out);
}

// Round 6
// 2612.982 us; speedup vs baseline: 1.6533x; 1.4390x over previous
//
#include <hip/hip_runtime.h>
#include <hip/hip_bf16.h>

#define S 4096
#define E 256
#define HH 256
#define TT 16
#define NEG_ -10000.0f
#define START_ 14
#define STOP_ 15

// ---------- fast math helpers (host-side kernels) ----------
__device__ __forceinline__ float fast_exp(float x) {           // e^x
    return __builtin_amdgcn_exp2f(x * 1.4426950408889634f);
}
__device__ __forceinline__ float fast_log(float x) {           // ln
    return 0.6931471805599453f * __builtin_amdgcn_logf(x);
}

// ---------- K0: quantize W_hh and h0 to int4 (per-row scale m/7) ----------
// One wave per row; lanes 0..31 each pack 8 consecutive values into 1 dword
// (nibble k = element 8*lane+k, two's-complement 4-bit).
__global__ __launch_bounds__(64) void quant4_kernel(
    const float* __restrict__ Wf, const float* __restrict__ Wb,
    const float* __restrict__ h0,
    int* __restrict__ wq4, float* __restrict__ wscale,
    int* __restrict__ hq0p, float* __restrict__ sh0)
{
    int blk = blockIdx.x, lane = threadIdx.x;
    const float* src;
    int* dst;
    float* scl;
    if (blk < 2048) {
        int d = blk >> 10, r = blk & 1023;
        src = (d == 0 ? Wf : Wb) + (size_t)r * 256;
        dst = wq4 + ((size_t)(d * 1024 + r)) * 32;
        scl = wscale + (d * 1024 + r);
    } else {
        int d = blk - 2048;
        src = h0 + (size_t)d * 256;
        dst = hq0p + d * 32;
        scl = sh0 + d;
    }
    float4 a = make_float4(0.f, 0.f, 0.f, 0.f), b = a;
    if (lane < 32) {
        a = ((const float4*)src)[2 * lane];
        b = ((const float4*)src)[2 * lane + 1];
    }
    float f[8] = {a.x, a.y, a.z, a.w, b.x, b.y, b.z, b.w};
    float m = 0.f;
    #pragma unroll
    for (int k = 0; k < 8; ++k) m = fmaxf(m, fabsf(f[k]));
    #pragma unroll
    for (int off = 1; off < 64; off <<= 1) m = fmaxf(m, __shfl_xor(m, off, 64));
    m = fmaxf(m, 1e-20f);
    float inv = 7.0f / m;
    if (lane < 32) {
        int dw = 0;
        #pragma unroll
        for (int k = 0; k < 8; ++k) {
            int q = __float2int_rn(f[k] * inv);
            q = max(-8, min(7, q));
            dw |= (q & 0xF) << (4 * k);
        }
        dst[lane] = dw;
    }
    if (lane == 0) *scl = m / 7.0f;
}

// ---------- K1: xg packed per lane-pair ----------
// lstm thread t reads float2 at byte [step*4096 + t*8]:
//   even t=2m:   (.x,.y) = rows (m, 256+m)      = (i,f)
//   odd  t=2m+1: (.x,.y) = rows (512+m, 768+m)  = (g,o)
__global__ __launch_bounds__(256) void xg_kernel(
    const int* __restrict__ sent, const float* __restrict__ embed,
    const float* __restrict__ Wf, const float* __restrict__ bihf, const float* __restrict__ bhhf,
    const float* __restrict__ Wb, const float* __restrict__ bihb, const float* __restrict__ bhhb,
    float* __restrict__ xg)
{
    const int dir = blockIdx.y;
    const int t0 = blockIdx.x * 16;
    const int tid = threadIdx.x;
    const float* W = dir ? Wb : Wf;
    __shared__ float xt[16][256];
    for (int tt = 0; tt < 16; ++tt) {
        int t = t0 + tt;
        int pos = dir ? (S - 1 - t) : t;
        int w = sent[pos];
        xt[tt][tid] = embed[(size_t)w * 256 + tid];
    }
    __syncthreads();
    float acc[4][16];
    #pragma unroll
    for (int rc = 0; rc < 4; ++rc)
        #pragma unroll
        for (int tt = 0; tt < 16; ++tt) acc[rc][tt] = 0.f;
    for (int e = 0; e < 256; ++e) {
        float xv[16];
        #pragma unroll
        for (int tt = 0; tt < 16; ++tt) xv[tt] = xt[tt][e];
        #pragma unroll
        for (int rc = 0; rc < 4; ++rc) {
            float w = W[(size_t)(rc * 256 + tid) * 256 + e];
            #pragma unroll
            for (int tt = 0; tt < 16; ++tt) acc[rc][tt] += w * xv[tt];
        }
    }
    const float* bih = dir ? bihb : bihf;
    const float* bhh = dir ? bhhb : bhhf;
    float b0 = bih[0 * 256 + tid] + bhh[0 * 256 + tid];
    float b1 = bih[1 * 256 + tid] + bhh[1 * 256 + tid];
    float b2 = bih[2 * 256 + tid] + bhh[2 * 256 + tid];
    float b3 = bih[3 * 256 + tid] + bhh[3 * 256 + tid];
    #pragma unroll
    for (int tt = 0; tt < 16; ++tt) {
        float4 v;
        v.x = acc[0][tt] + b0;
        v.y = acc[1][tt] + b1;
        v.z = acc[2][tt] + b2;
        v.w = acc[3][tt] + b3;
        ((float4*)(xg + ((size_t)dir * S + (t0 + tt)) * 1024))[tid] = v;
    }
}

// ---------- K2: sequential LSTM, int4 dot8 inline-asm inner loop ----------
// Pair layout: thread t, cell m=t>>1; even lane rows {m,256+m}=(i,f),
// odd lane rows {512+m,768+m}=(g,o). Weights int4: 32 dwords/row.
// Regs: WA v32-63, WB v64-95, h v96-127, accs v128-131, xa v132-135,
// addrs v136-139, temps v140-149, c v150, scales v151-152.
#define D8(a,w,h) "v_dot8_i32_i4 " a ", " w ", " h ", " a "\n\t"
#define CHK(h0,h1,h2,h3, a0,a1,a2,a3, b0,b1,b2,b3) \
  D8("v128",a0,h0) D8("v130",b0,h0) D8("v129",a1,h1) D8("v131",b1,h1) \
  D8("v128",a2,h2) D8("v130",b2,h2) D8("v129",a3,h3) D8("v131",b3,h3)

#define LSTM_BODY(XA0, XA1, BPAIR) \
  "global_load_dwordx2 " BPAIR ", v136, %[sxg]\n\t" \
  "ds_read_b128 v[96:99],   v138\n\t" \
  "ds_read_b128 v[100:103], v138 offset:16\n\t" \
  "ds_read_b128 v[104:107], v138 offset:32\n\t" \
  "ds_read_b128 v[108:111], v138 offset:48\n\t" \
  "ds_read_b128 v[112:115], v138 offset:64\n\t" \
  "ds_read_b128 v[116:119], v138 offset:80\n\t" \
  "ds_read_b128 v[120:123], v138 offset:96\n\t" \
  "ds_read_b128 v[124:127], v138 offset:112\n\t" \
  "v_mov_b32 v128, 0\n\t" \
  "v_mov_b32 v129, 0\n\t" \
  "v_mov_b32 v130, 0\n\t" \
  "v_mov_b32 v131, 0\n\t" \
  "s_waitcnt lgkmcnt(6)\n\t" \
  CHK("v96","v97","v98","v99",     "v32","v33","v34","v35", "v64","v65","v66","v67") \
  CHK("v100","v101","v102","v103", "v36","v37","v38","v39", "v68","v69","v70","v71") \
  "s_waitcnt lgkmcnt(4)\n\t" \
  CHK("v104","v105","v106","v107", "v40","v41","v42","v43", "v72","v73","v74","v75") \
  CHK("v108","v109","v110","v111", "v44","v45","v46","v47", "v76","v77","v78","v79") \
  "s_waitcnt lgkmcnt(2)\n\t" \
  CHK("v112","v113","v114","v115", "v48","v49","v50","v51", "v80","v81","v82","v83") \
  CHK("v116","v117","v118","v119", "v52","v53","v54","v55", "v84","v85","v86","v87") \
  "s_waitcnt lgkmcnt(0)\n\t" \
  CHK("v120","v121","v122","v123", "v56","v57","v58","v59", "v88","v89","v90","v91") \
  CHK("v124","v125","v126","v127", "v60","v61","v62","v63", "v92","v93","v94","v95") \
  "v_add_u32 v128, v128, v129\n\t" \
  "v_add_u32 v130, v130, v131\n\t" \
  "v_cvt_f32_i32 v140, v128\n\t" \
  "v_cvt_f32_i32 v141, v130\n\t" \
  "s_waitcnt vmcnt(2)\n\t" \
  "v_fma_f32 v142, v151, v140, " XA0 "\n\t" \
  "v_fma_f32 v143, v152, v141, " XA1 "\n\t" \
  "v_mov_b32 v151, %[s1f]\n\t" \
  "v_mov_b32 v152, %[s2f]\n\t" \
  "v_med3_f32 v142, v142, %[ncl], %[pcl]\n\t" \
  "v_mul_f32 v140, %[kk1], v142\n\t" \
  "v_mul_f32 v144, %[nk], v143\n\t" \
  "v_exp_f32 v140, v140\n\t" \
  "v_exp_f32 v144, v144\n\t" \
  "s_nop 1\n\t" \
  "v_fma_f32 v141, v140, %[mk], %[bk]\n\t" \
  "v_add_f32 v142, 1.0, v140\n\t" \
  "v_add_f32 v145, 1.0, v144\n\t" \
  "v_rcp_f32 v142, v142\n\t" \
  "v_rcp_f32 v145, v145\n\t" \
  "s_nop 1\n\t" \
  "v_mul_f32 v146, v141, v142\n\t" \
  "s_nop 1\n\t" \
  "v_mov_b32_dpp v147, v146 quad_perm:[1,0,3,2] row_mask:0xf bank_mask:0xf\n\t" \
  "v_mov_b32_dpp v148, v145 quad_perm:[1,0,3,2] row_mask:0xf bank_mask:0xf\n\t" \
  "v_cndmask_b32 v140, v146, v147, %[pm]\n\t" \
  "v_cndmask_b32 v141, v145, v148, %[pm]\n\t" \
  "v_cndmask_b32 v142, v147, v146, %[pm]\n\t" \
  "v_cndmask_b32 v143, v148, v145, %[pm]\n\t" \
  "v_mul_f32 v150, v141, v150\n\t" \
  "v_fmac_f32 v150, v140, v142\n\t" \
  "v_med3_f32 v140, v150, %[ncl], %[pcl]\n\t" \
  "v_mul_f32 v140, %[k2], v140\n\t" \
  "v_exp_f32 v140, v140\n\t" \
  "s_nop 1\n\t" \
  "v_add_f32 v141, -1.0, v140\n\t" \
  "v_add_f32 v142, 1.0, v140\n\t" \
  "v_rcp_f32 v142, v142\n\t" \
  "s_nop 1\n\t" \
  "v_mul_f32 v141, v141, v142\n\t" \
  "v_mul_f32 v144, v143, v141\n\t" \
  "global_store_dword v137, v144, %[shs]\n\t" \
  "v_mul_f32 v140, %[c7], v144\n\t" \
  "v_rndne_f32 v140, v140\n\t" \
  "v_cvt_i32_f32 v140, v140\n\t" \
  "v_and_b32 v140, 15, v140\n\t" \
  "s_nop 1\n\t" \
  "v_mov_b32_dpp v141, v140 quad_perm:[2,3,0,1] row_mask:0xf bank_mask:0xf\n\t" \
  "v_lshlrev_b32 v141, 4, v141\n\t" \
  "v_or_b32 v140, v140, v141\n\t" \
  "ds_write_b8 v139, v140\n\t" \
  "v_add_u32 v136, 0x1000, v136\n\t" \
  "v_add_u32 v137, 0x400, v137\n\t" \
  "v_xor_b32 v138, 0x80, v138\n\t" \
  "v_xor_b32 v139, 0x80, v139\n\t" \
  "s_waitcnt lgkmcnt(0)\n\t" \
  "s_barrier\n\t"

__global__ __launch_bounds__(512, 2) void lstm_kernel(
    const float* __restrict__ xg, const int* __restrict__ wq4,
    const float* __restrict__ wscale, const int* __restrict__ hq0p,
    const float* __restrict__ sh0, const float* __restrict__ c0,
    float* __restrict__ hs)
{
    const int d = blockIdx.x;
    const int t = threadIdx.x;
    const int m = t >> 1;          // cell 0..255
    const int odd = t & 1;
    const int r1 = odd * 512 + m;  // i (even) / g (odd)
    const int r2 = r1 + 256;       // f (even) / o (odd)

    __shared__ alignas(16) int hq4buf[128];   // 512B: buf0 @0, buf1 @128, dump @256

    const int*   wq_d = wq4 + (size_t)d * 32768;
    const float* xg_d = xg + (size_t)d * S * 1024;
    float*       hs_d = hs + (size_t)d * S * 256;
    const float s1 = wscale[d * 1024 + r1];
    const float s2 = wscale[d * 1024 + r2];
    const float sh0v = sh0[d];
    const float c0v = c0[d * 256 + m];
    const int h0v = hq0p[d * 32 + (t & 31)];
    const unsigned h0a  = (unsigned)(t & 31) * 4u;
    const unsigned xoff = (unsigned)t * 8u;
    const unsigned hoff = (unsigned)m * 4u;
    const unsigned voA  = (unsigned)r1 * 128u;
    const unsigned voB  = (unsigned)r2 * 128u;
    // h write addr: quad leader (t&3==0) writes byte (t>>2) of buf1;
    // other lanes dump to [256,448)
    const unsigned waddr = ((t & 3) == 0) ? (128u + (unsigned)(t >> 2))
                                          : (256u + (unsigned)(t & 63));
    const float sc1i = s1 * sh0v, sc2i = s2 * sh0v;          // step-0 scales
    const float sc1f = s1 * (1.0f / 7.0f);                   // steady-state
    const float sc2f = s2 * (1.0f / 7.0f);
    const float kk1 = odd ? 2.8853900817779268f : -1.4426950408889634f;
    const float mkv = odd ? 1.0f : 0.0f;
    const float bkv = odd ? -1.0f : 1.0f;
    const float nkv = -1.4426950408889634f;
    const float k2v = 2.8853900817779268f;
    const float c7 = 7.0f;
    const float nclv = -30.0f, pclv = 30.0f;
    const unsigned long long pmask = 0xAAAAAAAAAAAAAAAAULL;  // odd lanes
    const unsigned lds_keep = (unsigned)(size_t)&hq4buf[0];
    int cnt = S / 2;   // body unrolled x2

    asm volatile(
        // ---- prologue ----
        "v_mov_b32 v136, %[xoff]\n\t"
        "v_mov_b32 v137, %[hoff]\n\t"
        "v_mov_b32 v138, 0\n\t"
        "v_mov_b32 v139, %[wad]\n\t"
        "v_mov_b32 v150, %[c0v]\n\t"
        "v_mov_b32 v151, %[s1i]\n\t"
        "v_mov_b32 v152, %[s2i]\n\t"
        "ds_write_b32 %[h0a], %[h0v]\n\t"
        "global_load_dwordx4 v[32:35], %[voA], %[swq]\n\t"
        "global_load_dwordx4 v[36:39], %[voA], %[swq] offset:16\n\t"
        "global_load_dwordx4 v[40:43], %[voA], %[swq] offset:32\n\t"
        "global_load_dwordx4 v[44:47], %[voA], %[swq] offset:48\n\t"
        "global_load_dwordx4 v[48:51], %[voA], %[swq] offset:64\n\t"
        "global_load_dwordx4 v[52:55], %[voA], %[swq] offset:80\n\t"
        "global_load_dwordx4 v[56:59], %[voA], %[swq] offset:96\n\t"
        "global_load_dwordx4 v[60:63], %[voA], %[swq] offset:112\n\t"
        "global_load_dwordx4 v[64:67], %[voB], %[swq]\n\t"
        "global_load_dwordx4 v[68:71], %[voB], %[swq] offset:16\n\t"
        "global_load_dwordx4 v[72:75], %[voB], %[swq] offset:32\n\t"
        "global_load_dwordx4 v[76:79], %[voB], %[swq] offset:48\n\t"
        "global_load_dwordx4 v[80:83], %[voB], %[swq] offset:64\n\t"
        "global_load_dwordx4 v[84:87], %[voB], %[swq] offset:80\n\t"
        "global_load_dwordx4 v[88:91], %[voB], %[swq] offset:96\n\t"
        "global_load_dwordx4 v[92:95], %[voB], %[swq] offset:112\n\t"
        "global_load_dwordx2 v[132:133], v136, %[sxg]\n\t"
        "v_add_u32 v136, 0x1000, v136\n\t"
        "s_waitcnt vmcnt(0) lgkmcnt(0)\n\t"
        "s_barrier\n\t"
        // ---- main loop: 2 steps per iteration ----
        "Llstm%=:\n\t"
        LSTM_BODY("v132", "v133", "v[134:135]")
        LSTM_BODY("v134", "v135", "v[132:133]")
        "s_add_i32 %[cnt], %[cnt], -1\n\t"
        "s_cmp_lg_u32 %[cnt], 0\n\t"
        "s_cbranch_scc1 Llstm%=\n\t"
        : [cnt] "+s"(cnt)
        : [sxg] "s"(xg_d), [shs] "s"(hs_d), [swq] "s"(wq_d), [pm] "s"(pmask),
          [xoff] "v"(xoff), [hoff] "v"(hoff), [wad] "v"(waddr), [c0v] "v"(c0v),
          [s1i] "v"(sc1i), [s2i] "v"(sc2i), [s1f] "v"(sc1f), [s2f] "v"(sc2f),
          [kk1] "v"(kk1), [mk] "v"(mkv), [bk] "v"(bkv), [nk] "v"(nkv),
          [k2] "v"(k2v), [c7] "v"(c7), [ncl] "v"(nclv), [pcl] "v"(pclv),
          [voA] "v"(voA), [voB] "v"(voB), [h0a] "v"(h0a), [h0v] "v"(h0v),
          [keep] "v"(lds_keep)
        : "memory", "scc",
          "v32","v33","v34","v35","v36","v37","v38","v39",
          "v40","v41","v42","v43","v44","v45","v46","v47",
          "v48","v49","v50","v51","v52","v53","v54","v55",
          "v56","v57","v58","v59","v60","v61","v62","v63",
          "v64","v65","v66","v67","v68","v69","v70","v71",
          "v72","v73","v74","v75","v76","v77","v78","v79",
          "v80","v81","v82","v83","v84","v85","v86","v87",
          "v88","v89","v90","v91","v92","v93","v94","v95",
          "v96","v97","v98","v99","v100","v101","v102","v103",
          "v104","v105","v106","v107","v108","v109","v110","v111",
          "v112","v113","v114","v115","v116","v117","v118","v119",
          "v120","v121","v122","v123","v124","v125","v126","v127",
          "v128","v129","v130","v131","v132","v133","v134","v135",
          "v136","v137","v138","v139","v140","v141","v142","v143",
          "v144","v145","v146","v147","v148","v149","v150","v151","v152");
}

// ---------- K3: feats[t][tag] = b_out[tag] + W_out[tag] . [hf[t], hb[t]] ----------
__global__ __launch_bounds__(256) void feats_kernel(
    const float* __restrict__ hs, const float* __restrict__ Wout,
    const float* __restrict__ bout, float* __restrict__ feats)
{
    __shared__ float Wl[16][513];
    int tid = threadIdx.x;
    for (int i = tid; i < 16 * 512; i += 256) Wl[i >> 9][i & 511] = Wout[i];
    __syncthreads();
    int tt = tid >> 4, tag = tid & 15;
    int tcur = blockIdx.x * 16 + tt;
    const float* hf = hs + (size_t)tcur * 256;
    const float* hb = hs + (size_t)S * 256 + (size_t)(S - 1 - tcur) * 256;
    float acc = bout[tag];
    for (int k = 0; k < 256; ++k) acc += Wl[tag][k] * hf[k];
    for (int k = 0; k < 256; ++k) acc += Wl[tag][256 + k] * hb[k];
    feats[(size_t)tcur * 16 + tag] = acc;
}

// ---------- K4a: CRF chunk products in log semiring ----------
__global__ __launch_bounds__(256) void crf_chunk_kernel(
    const float* __restrict__ feats, const float* __restrict__ trans,
    float* __restrict__ P)
{
    int chunk = blockIdx.x;
    int tid = threadIdx.x;
    int i = tid >> 4, jj = tid & 15;
    __shared__ float Mt[2][16][17];   // Mt[buf][j][k] = M[k][j]
    float tr[16];
    #pragma unroll
    for (int k = 0; k < 16; ++k) tr[k] = trans[i * 16 + k];
    int t0 = chunk * 64;
    float emit = feats[(size_t)t0 * 16 + i];
    Mt[0][jj][i] = tr[jj] + emit;     // init M = A_{t0}
    __syncthreads();
    int cur = 0;
    float em_next = feats[(size_t)(t0 + 1) * 16 + i];
    for (int s = 1; s < 64; ++s) {
        float em = em_next;
        if (s + 1 < 64) em_next = feats[(size_t)(t0 + s + 1) * 16 + i];
        float v[16];
        #pragma unroll
        for (int k = 0; k < 16; ++k) v[k] = tr[k] + Mt[cur][jj][k];
        float m = v[0];
        #pragma unroll
        for (int k = 1; k < 16; ++k) m = fmaxf(m, v[k]);
        float ssum = 0.f;
        #pragma unroll
        for (int k = 0; k < 16; ++k) ssum += fast_exp(v[k] - m);
        float nv = em + m + fast_log(ssum);
        Mt[cur ^ 1][jj][i] = nv;
        cur ^= 1;
        __syncthreads();
    }
    P[((size_t)chunk * 16 + i) * 16 + jj] = Mt[cur][jj][i];
}

// ---------- K4b: fold 64 chunk matrices through alpha ----------
__global__ __launch_bounds__(256) void crf_fold_kernel(
    const float* __restrict__ P, const float* __restrict__ trans,
    float* __restrict__ out)
{
    int tid = threadIdx.x;
    int i = tid >> 4, jj = tid & 15;
    __shared__ float alpha[16];
    if (tid < 16) alpha[tid] = (tid == START_) ? 0.0f : NEG_;
    __syncthreads();
    for (int cc = 0; cc < 64; ++cc) {
        float pv = P[((size_t)cc * 16 + i) * 16 + jj];
        float v = pv + alpha[jj];
        float m = v;
        #pragma unroll
        for (int off = 1; off < 16; off <<= 1) m = fmaxf(m, __shfl_xor(m, off, 64));
        float e = fast_exp(v - m);
        #pragma unroll
        for (int off = 1; off < 16; off <<= 1) e += __shfl_xor(e, off, 64);
        float nv = m + fast_log(e);
        __syncthreads();
        if (jj == 0) alpha[i] = nv;
        __syncthreads();
    }
    if (tid < 16) {
        float v = alpha[tid] + trans[STOP_ * 16 + tid];
        float m = v;
        #pragma unroll
        for (int off = 1; off < 16; off <<= 1) m = fmaxf(m, __shfl_xor(m, off, 64));
        float e = fast_exp(v - m);
        #pragma unroll
        for (int off = 1; off < 16; off <<= 1) e += __shfl_xor(e, off, 64);
        if (tid == 0) out[0] = m + fast_log(e);
    }
}

extern "C" void kernel_launch(void* const* d_in, const int* in_sizes, int n_in,
                              void* d_out, int out_size, void* d_ws, size_t ws_size,
                              hipStream_t stream) {
    const int*   sent  = (const int*)d_in[0];
    const float* embed = (const float*)d_in[1];
    const float* Wihf  = (const float*)d_in[2];
    const float* Whhf  = (const float*)d_in[3];
    const float* bihf  = (const float*)d_in[4];
    const float* bhhf  = (const float*)d_in[5];
    const float* Wihb  = (const float*)d_in[6];
    const float* Whhb  = (const float*)d_in[7];
    const float* bihb  = (const float*)d_in[8];
    const float* bhhb  = (const float*)d_in[9];
    const float* Wout  = (const float*)d_in[10];
    const float* bout  = (const float*)d_in[11];
    const float* trans = (const float*)d_in[12];
    const float* h0    = (const float*)d_in[13];
    const float* c0    = (const float*)d_in[14];
    float* out = (float*)d_out;

    char* ws = (char*)d_ws;
    constexpr size_t OFF_XG     = 0;                                      // 32MB
    constexpr size_t OFF_WQ     = OFF_XG + (size_t)2 * S * 1024 * 4;      // 256KB (int4)
    constexpr size_t OFF_WSCALE = OFF_WQ + (size_t)2 * 1024 * 32 * 4;     // 8KB
    constexpr size_t OFF_HQ0    = OFF_WSCALE + 2 * 1024 * 4;              // 256B
    constexpr size_t OFF_SH0    = OFF_HQ0 + 2 * 32 * 4;                   // pad 256B
    constexpr size_t OFF_HS     = OFF_SH0 + 256;                          // 8MB
    constexpr size_t OFF_FEATS  = OFF_HS + (size_t)2 * S * 256 * 4;       // 256KB
    constexpr size_t OFF_P      = OFF_FEATS + (size_t)S * 16 * 4;         // 64KB

    float* xg     = (float*)(ws + OFF_XG);
    int*   wq4    = (int*)(ws + OFF_WQ);
    float* wscale = (float*)(ws + OFF_WSCALE);
    int*   hq0p   = (int*)(ws + OFF_HQ0);
    float* sh0    = (float*)(ws + OFF_SH0);
    float* hs     = (float*)(ws + OFF_HS);
    float* feats  = (float*)(ws + OFF_FEATS);
    float* P      = (float*)(ws + OFF_P);

    quant4_kernel<<<dim3(2050), dim3(64), 0, stream>>>(Whhf, Whhb, h0, wq4, wscale, hq0p, sh0);
    xg_kernel<<<dim3(256, 2), dim3(256), 0, stream>>>(sent, embed, Wihf, bihf, bhhf,
                                                      Wihb, bihb, bhhb, xg);
    lstm_kernel<<<dim3(2), dim3(512), 0, stream>>>(xg, wq4, wscale, hq0p, sh0, c0, hs);
    feats_kernel<<<dim3(256), dim3(256), 0, stream>>>(hs, Wout, bout, feats);
    crf_chunk_kernel<<<dim3(64), dim3(256), 0, stream>>>(feats, trans, P);
    crf_fold_kernel<<<dim3(1), dim3(256), 0, stream>>>(P, trans, out);
}